// Round 5
// baseline (52.461 us; speedup 1.0000x reference)
//
#include <hip/hip_runtime.h>
#include <hip/hip_cooperative_groups.h>
#include <math.h>

namespace cg = cooperative_groups;

// Problem constants (from reference setup_inputs)
#define B 8
#define S 512
#define G 16
#define DA 1024
#define DM 256
#define WIN 12
#define NCHUNK 32                 // s-chunks for partial max (256 blocks)
#define ROWS (S / NCHUNK)         // 16 rows per chunk
#define DTOT (DA + DM)            // 1280 pooled dims
#define NW 8                      // waves per block (512 threads)
#define RPW (ROWS / NW)           // 2 rows per wave in phase 1

__inline__ __device__ float4 fmax4(float4 a, float4 b) {
    return make_float4(fmaxf(a.x, b.x), fmaxf(a.y, b.y),
                       fmaxf(a.z, b.z), fmaxf(a.w, b.w));
}
__inline__ __device__ float dot4(float4 a, float4 b) {
    return a.x * b.x + a.y * b.y + a.z * b.z + a.w * b.w;
}

// 8-wave (512-thread) batched block reduce: 4 sums in one LDS round.
__inline__ __device__ float4 blockReduceSum4_8(float4 v, float4* sh) {
    int lane = threadIdx.x & 63, w = threadIdx.x >> 6;
#pragma unroll
    for (int o = 32; o > 0; o >>= 1) {
        v.x += __shfl_xor(v.x, o, 64);
        v.y += __shfl_xor(v.y, o, 64);
        v.z += __shfl_xor(v.z, o, 64);
        v.w += __shfl_xor(v.w, o, 64);
    }
    __syncthreads();
    if (lane == 0) sh[w] = v;
    __syncthreads();
    float4 r = sh[0];
#pragma unroll
    for (int ww = 1; ww < NW; ++ww) {
        r.x += sh[ww].x; r.y += sh[ww].y; r.z += sh[ww].z; r.w += sh[ww].w;
    }
    return r;
}

// Single cooperative kernel.
// Phase 1 (all 256 blocks): sweep att+mod once -> per-row projections + pmax.
// grid.sync()
// Phase 2 (blocks 0..127): one logit each.
__global__ __launch_bounds__(512) void k_all(
    const float* __restrict__ att, const float* __restrict__ mod,
    const float* __restrict__ Wa, const float* __restrict__ Wm,
    const float* __restrict__ ba, const float* __restrict__ bm,
    const int* __restrict__ gidx, const int* __restrict__ mask,
    float* __restrict__ proj0a, float* __restrict__ proj2a,
    float* __restrict__ proj0m, float* __restrict__ proj2m,
    float* __restrict__ pmax, float* __restrict__ out)
{
    __shared__ float part[NW][DTOT];   // 40 KB, reused by both phases
    __shared__ float4 s4[NW];
    const int t = threadIdx.x, lane = t & 63, w = t >> 6;

    // ---------------- Phase 1: projections + partial maxes ----------------
    {
        const int ch = blockIdx.x, b = blockIdx.y;

        const float4* W0 = (const float4*)Wa;             // W_att[0:1024)
        const float4* W2 = (const float4*)(Wa + 2 * DA);  // W_att[2048:3072)
        float4 w0[4], w2[4];
#pragma unroll
        for (int k = 0; k < 4; ++k) {
            w0[k] = W0[lane + 64 * k];
            w2[k] = W2[lane + 64 * k];
        }
        const float4 wq0 = ((const float4*)Wm)[lane];             // W_mod[0:256)
        const float4 wq2 = ((const float4*)(Wm + 2 * DM))[lane];  // W_mod[512:768)

        float4 amax[4], mmax;
#pragma unroll
        for (int k = 0; k < 4; ++k)
            amax[k] = make_float4(-INFINITY, -INFINITY, -INFINITY, -INFINITY);
        mmax = make_float4(-INFINITY, -INFINITY, -INFINITY, -INFINITY);

        const int srow0 = ch * ROWS + w * RPW;
#pragma unroll
        for (int r = 0; r < RPW; ++r) {
            const int row = b * S + srow0 + r;
            const float4* arow = (const float4*)(att + (size_t)row * DA);
            float p0 = 0.f, p2 = 0.f;
#pragma unroll
            for (int k = 0; k < 4; ++k) {
                float4 va = arow[lane + 64 * k];
                p0 += dot4(va, w0[k]);
                p2 += dot4(va, w2[k]);
                amax[k] = fmax4(amax[k], va);
            }
            float4 vm = ((const float4*)(mod + (size_t)row * DM))[lane];
            float q0 = dot4(vm, wq0);
            float q2 = dot4(vm, wq2);
            mmax = fmax4(mmax, vm);

#pragma unroll
            for (int o = 32; o > 0; o >>= 1) {
                p0 += __shfl_xor(p0, o, 64);
                p2 += __shfl_xor(p2, o, 64);
                q0 += __shfl_xor(q0, o, 64);
                q2 += __shfl_xor(q2, o, 64);
            }
            if (lane == 0) {
                proj0a[row] = p0;
                proj2a[row] = p2;
                proj0m[row] = q0;
                proj2m[row] = q2;
            }
        }

        // Publish per-wave partial maxes.
        float4* pr = (float4*)&part[w][0];
#pragma unroll
        for (int k = 0; k < 4; ++k) pr[lane + 64 * k] = amax[k];
        ((float4*)&part[w][DA])[lane] = mmax;
        __syncthreads();

        // Cross-wave max; stride 1280 ≡ 0 mod 32 banks -> conflict-free.
        for (int d = t; d < DTOT; d += 512) {
            float m = part[0][d];
#pragma unroll
            for (int ww = 1; ww < NW; ++ww) m = fmaxf(m, part[ww][d]);
            pmax[((size_t)b * NCHUNK + ch) * DTOT + d] = m;
        }
    }

    cg::this_grid().sync();

    // ---------------- Phase 2: one logit per block (first 128 blocks) -----
    const int bid = blockIdx.y * NCHUNK + blockIdx.x;
    if (bid >= B * G) return;
    const int g = bid & (G - 1), b = bid >> 4;
    const int gi = gidx[b * G + g];

    if (g == 0) {
        // Global row: unmasked proj2 sums, mask count, max-dot from pmax.
        float sa = 0.f, sm = 0.f, cm = 0.f;
        for (int s = t; s < S; s += 512) {
            sa += proj2a[b * S + s];
            sm += proj2m[b * S + s];
            cm += (float)mask[b * S + s];
        }
        float gm = 0.f;
        for (int d = t; d < DTOT; d += 512) {
            float m = -INFINITY;
#pragma unroll
            for (int ch = 0; ch < NCHUNK; ++ch)
                m = fmaxf(m, pmax[((size_t)b * NCHUNK + ch) * DTOT + d]);
            float wgt = (d < DA) ? Wa[DA + d] : Wm[DM + (d - DA)];
            gm += wgt * m;
        }
        float4 r = blockReduceSum4_8(make_float4(sa, sm, cm, gm), s4);
        if (t == 0) {
            out[b * G + 0] = proj0a[b * S + gi] + proj0m[b * S + gi] + r.w +
                             r.x / r.z + r.y / r.z + ba[0] + bm[0];
        }
    } else {
        int lo = gi - WIN; if (lo < 0) lo = 0;
        int hi = gi + WIN; if (hi > S - 1) hi = S - 1;

        // Windowed per-d max (clamped at 0 by the reference's x*wmf form;
        // 25 < 512 always leaves out-of-window zeros). Wave w handles
        // s = lo+w, lo+w+8, ... -> serial depth <= 4.
        float4 amax2[4];
#pragma unroll
        for (int k = 0; k < 4; ++k) amax2[k] = make_float4(0.f, 0.f, 0.f, 0.f);
        float4 mmax2 = make_float4(0.f, 0.f, 0.f, 0.f);
        float sa = 0.f, sm = 0.f, cn = 0.f;

        for (int s = lo + w; s <= hi; s += NW) {
            if (mask[b * S + s] > 0) {
                const int row = b * S + s;
                const float4* arow = (const float4*)(att + (size_t)row * DA);
#pragma unroll
                for (int k = 0; k < 4; ++k)
                    amax2[k] = fmax4(amax2[k], arow[lane + 64 * k]);
                mmax2 = fmax4(mmax2, ((const float4*)(mod + (size_t)row * DM))[lane]);
                if (lane == 0) {
                    sa += proj2a[row];
                    sm += proj2m[row];
                    cn += 1.f;
                }
            }
        }

        // Merge 8 waves' maxes through LDS (same layout as phase 1).
        float4* pr = (float4*)&part[w][0];
#pragma unroll
        for (int k = 0; k < 4; ++k) pr[lane + 64 * k] = amax2[k];
        ((float4*)&part[w][DA])[lane] = mmax2;
        __syncthreads();

        float wdot = 0.f;
        for (int d = t; d < DTOT; d += 512) {
            float m = part[0][d];
#pragma unroll
            for (int ww = 1; ww < NW; ++ww) m = fmaxf(m, part[ww][d]);
            float wgt = (d < DA) ? Wa[DA + d] : Wm[DM + (d - DA)];
            wdot += wgt * m;
        }
        float4 r = blockReduceSum4_8(make_float4(wdot, sa, sm, cn), s4);
        if (t == 0) {
            out[b * G + g] = proj0a[b * S + gi] + proj0m[b * S + gi] +
                             r.x + r.y / r.w + r.z / r.w + ba[0] + bm[0];
        }
    }
}

extern "C" void kernel_launch(void* const* d_in, const int* in_sizes, int n_in,
                              void* d_out, int out_size, void* d_ws, size_t ws_size,
                              hipStream_t stream) {
    const float* att  = (const float*)d_in[0];
    const float* mod  = (const float*)d_in[1];
    const float* Wa   = (const float*)d_in[2];
    const float* ba   = (const float*)d_in[3];
    const float* Wm   = (const float*)d_in[4];
    const float* bm   = (const float*)d_in[5];
    // d_in[6] = q_enc (unused by reference)
    const int* gidx   = (const int*)d_in[7];
    const int* mask   = (const int*)d_in[8];
    // d_in[9] = q_mask (unused by reference)
    float* out = (float*)d_out;

    // Workspace layout (floats)
    float* ws     = (float*)d_ws;
    float* proj0a = ws;                 // B*S
    float* proj2a = proj0a + B * S;     // B*S
    float* proj0m = proj2a + B * S;     // B*S
    float* proj2m = proj0m + B * S;     // B*S
    float* pmax   = proj2m + B * S;     // B*NCHUNK*DTOT

    void* args[] = {
        (void*)&att, (void*)&mod, (void*)&Wa, (void*)&Wm,
        (void*)&ba, (void*)&bm, (void*)&gidx, (void*)&mask,
        (void*)&proj0a, (void*)&proj2a, (void*)&proj0m, (void*)&proj2m,
        (void*)&pmax, (void*)&out
    };
    hipLaunchCooperativeKernel((void*)k_all, dim3(NCHUNK, B), dim3(512),
                               args, 0, stream);
}